// Round 11
// baseline (550.883 us; speedup 1.0000x reference)
//
#include <hip/hip_runtime.h>
#include <math.h>

#define DEV __device__ __forceinline__

namespace {
constexpr int B_ = 32, H_ = 256, W_ = 256;
constexpr size_t NPIX = (size_t)B_ * H_ * W_;   // 2,097,152

// ---- qstep global table block (float offsets) ----
constexpr int QT9 = 0;            // [9][33] entries stride20: T9[t][code][o] (+b1 baked at t==4)
constexpr int QAB = 5940;         // A2: 32 entries stride20; then Bc: 32 entries stride20
constexpr int QCB = 7220;         // 32 entries stride20: cb + |cb|^2 (uniform -> SMEM)
constexpr int QU2 = 7860;         // 16 entries stride16: up2w^T (uniform -> SMEM)
constexpr int QTOT = 8116;
constexpr int QLDS = 7220;        // floats staged to LDS (divergent-gather tables: T9 + A2/Bc)

// ---- iter1 global table block ----
constexpr int IW1 = 0;            // [9*16] entries stride16: w1[t][i][o]
constexpr int IU2 = 2304;         // 16 entries stride16: up2w^T [i][o]
constexpr int ITA = 2560;         // 16 entries stride16: tauw^T [i][c]
constexpr int ICB = 2816;         // 32 entries stride20: cb + |cb|^2 at +16
constexpr int IB1 = 3456;
constexpr int IB2 = 3472;
constexpr int ITB = 3488;
constexpr int ISB = 3504;
constexpr int ISW = 3520;         // 9 entries stride16
constexpr int ITOT = 3664;

// ws byte offsets
constexpr size_t OFF_QTAB = 2 * NPIX;
constexpr size_t OFF_ITAB = OFF_QTAB + (size_t)QTOT * 4;
constexpr size_t OFF_DLUT = OFF_ITAB + (size_t)ITOT * 4;
constexpr size_t OFF_LOSS = (OFF_DLUT + 128 + 7) & ~(size_t)7;
constexpr size_t OFF_MASK = OFF_LOSS + 5 * 8;
}

typedef float f2v __attribute__((ext_vector_type(2)));

struct V16 { f2v h[8]; };

DEV f2v fma2(f2v a, f2v b, f2v c) {       // a*b + c, elementwise (-> v_pk_fma_f32)
#if __has_builtin(__builtin_elementwise_fma)
    return __builtin_elementwise_fma(a, b, c);
#else
    f2v r; r.x = fmaf(a.x, b.x, c.x); r.y = fmaf(a.y, b.y, c.y); return r;
#endif
}
DEV f2v max2(f2v a, f2v b) {
#if __has_builtin(__builtin_elementwise_max)
    return __builtin_elementwise_max(a, b);
#else
    f2v r; r.x = fmaxf(a.x, b.x); r.y = fmaxf(a.y, b.y); return r;
#endif
}

DEV V16 v16z() {
    V16 r;
    #pragma unroll
    for (int j = 0; j < 8; ++j) r.h[j] = (f2v){0.f, 0.f};
    return r;
}
DEV void v16fma(V16& a, const V16& w, float s) {
    f2v ss = (f2v){s, s};
    #pragma unroll
    for (int j = 0; j < 8; ++j) a.h[j] = fma2(w.h[j], ss, a.h[j]);
}
DEV void v16add(V16& a, const V16& b) {
    #pragma unroll
    for (int j = 0; j < 8; ++j) a.h[j] = a.h[j] + b.h[j];
}
DEV void v16relu(V16& a) {
    f2v z = (f2v){0.f, 0.f};
    #pragma unroll
    for (int j = 0; j < 8; ++j) a.h[j] = max2(a.h[j], z);
}
DEV float v16dot(const V16& a, const V16& b) {
    f2v acc = (f2v){0.f, 0.f};
    #pragma unroll
    for (int j = 0; j < 8; ++j) acc = fma2(a.h[j], b.h[j], acc);
    return acc.x + acc.y;
}
DEV V16 ld16(const float* p) {            // 4x ds_read_b128 / s_load
    const float4* q = (const float4*)p;
    float4 A = q[0], Bv = q[1], C = q[2], D = q[3];
    V16 r;
    r.h[0] = (f2v){A.x, A.y};  r.h[1] = (f2v){A.z, A.w};
    r.h[2] = (f2v){Bv.x, Bv.y}; r.h[3] = (f2v){Bv.z, Bv.w};
    r.h[4] = (f2v){C.x, C.y};  r.h[5] = (f2v){C.z, C.w};
    r.h[6] = (f2v){D.x, D.y};  r.h[7] = (f2v){D.z, D.w};
    return r;
}
DEV void st16(float* p, const V16& v) {
    float4* q = (float4*)p;
    q[0] = make_float4(v.h[0].x, v.h[0].y, v.h[1].x, v.h[1].y);
    q[1] = make_float4(v.h[2].x, v.h[2].y, v.h[3].x, v.h[3].y);
    q[2] = make_float4(v.h[4].x, v.h[4].y, v.h[5].x, v.h[5].y);
    q[3] = make_float4(v.h[6].x, v.h[6].y, v.h[7].x, v.h[7].y);
}
DEV void v16sig(V16& a) {
    #pragma unroll
    for (int j = 0; j < 8; ++j) {
        a.h[j].x = 1.f / (1.f + expf(-a.h[j].x));
        a.h[j].y = 1.f / (1.f + expf(-a.h[j].y));
    }
}

// ---- one 4-px qstep group (exact R10 inner structure) ----
// K[3][6]: codes for rows r-1..r+1, cols c-1..c+4. Produces bk/best per px.
DEV void group4(const float* tab, const float* __restrict__ gQ,
                const int K[3][6], int bk[4], float best[4])
{
    V16 V[4];
    #pragma unroll
    for (int half = 0; half < 2; ++half) {
        const int p0 = half * 2, p1 = half * 2 + 1;
        V16 U0 = v16z(), U1 = v16z();
        #pragma unroll
        for (int t = 0; t < 9; ++t) {       // up1 = 9 gather-adds per px (LDS)
            const int dy = t / 3, dx = t % 3;
            V16 e0 = ld16(&tab[(t * 33 + K[dy][p0 + dx]) * 20]);
            v16add(U0, e0);
            V16 e1 = ld16(&tab[(t * 33 + K[dy][p1 + dx]) * 20]);
            v16add(U1, e1);
        }
        v16relu(U0); v16relu(U1);
        // up2 (uniform weights from global -> SMEM; b2 baked into A2)
        V16 v0 = v16z(), v1 = v16z();
        #pragma unroll
        for (int j = 0; j < 8; ++j) {
            f2v a0 = U0.h[j], a1 = U1.h[j];
            V16 wA = ld16(&gQ[QU2 + (2 * j) * 16]);
            v16fma(v0, wA, a0.x); v16fma(v1, wA, a1.x);
            V16 wB = ld16(&gQ[QU2 + (2 * j + 1) * 16]);
            v16fma(v0, wB, a0.y); v16fma(v1, wB, a1.y);
        }
        // blend via per-code tables (LDS gather): z = A2[kc] + Bc[kc]*v
        {
            int kc = K[1][p0 + 1];
            V16 a = ld16(&tab[QAB + kc * 20]);
            V16 bb = ld16(&tab[QAB + (32 + kc) * 20]);
            #pragma unroll
            for (int j = 0; j < 8; ++j) v0.h[j] = fma2(bb.h[j], v0.h[j], a.h[j]);
        }
        {
            int kc = K[1][p1 + 1];
            V16 a = ld16(&tab[QAB + kc * 20]);
            V16 bb = ld16(&tab[QAB + (32 + kc) * 20]);
            #pragma unroll
            for (int j = 0; j < 8; ++j) v1.h[j] = fma2(bb.h[j], v1.h[j], a.h[j]);
        }
        V[p0] = v0; V[p1] = v1;
    }
    // VQ: codebook streamed once (uniform from global -> SGPRs)
    float zz[4];
    #pragma unroll
    for (int p = 0; p < 4; ++p) { zz[p] = v16dot(V[p], V[p]); best[p] = 3.4e38f; bk[p] = 0; }
    #pragma unroll 4
    for (int k = 0; k < 32; ++k) {
        V16 q = ld16(&gQ[QCB + k * 20]);
        float cn = gQ[QCB + k * 20 + 16];
        #pragma unroll
        for (int p = 0; p < 4; ++p) {
            float d = (zz[p] + cn) - 2.0f * v16dot(q, V[p]);
            if (d < best[p]) { best[p] = d; bk[p] = k; }
        }
    }
}

// ---------------- setup: parallel across 16 blocks ----------------
__global__ void k_setup(const float* __restrict__ w1, const float* __restrict__ b1,
                        const float* __restrict__ u2w, const float* __restrict__ b2,
                        const float* __restrict__ tw, const float* __restrict__ tb,
                        const float* __restrict__ cb, const float* __restrict__ stw,
                        const float* __restrict__ stb, const float* __restrict__ dw,
                        const float* __restrict__ db,
                        float* __restrict__ gQ, float* __restrict__ gI,
                        float* __restrict__ dlut, double* __restrict__ lossS,
                        unsigned int* __restrict__ maskS)
{
    const int tid = threadIdx.x;
    const int gtid = blockIdx.x * 256 + tid;    // 0..4095
    if (gtid < 5) { lossS[gtid] = 0.0; maskS[gtid] = 0u; }
    for (int p = gtid; p < 297 * 16; p += 4096) {   // T9 entry-output pairs
        int e = p >> 4, o = p & 15;
        int t = e / 33, k = e % 33;
        float acc = 0.f;
        if (k < 32) {
            for (int i = 0; i < 16; ++i)
                acc = fmaf(w1[o * 144 + i * 9 + t], cb[k * 16 + i], acc);
            if (t == 4) acc += b1[o];
        }
        gQ[QT9 + e * 20 + o] = acc;
    }
    for (int e = gtid; e < 297; e += 4096) {        // T9 pads
        gQ[QT9 + e * 20 + 16] = 0.f; gQ[QT9 + e * 20 + 17] = 0.f;
        gQ[QT9 + e * 20 + 18] = 0.f; gQ[QT9 + e * 20 + 19] = 0.f;
    }
    for (int p = gtid; p < 144 * 16; p += 4096) {   // w1 rearranged [t][i][o]
        int e = p >> 4, o = p & 15;
        int t = e / 16, i = e % 16;
        gI[IW1 + e * 16 + o] = w1[o * 144 + i * 9 + t];
    }
    if (blockIdx.x != 0) return;
    if (tid < 32) {
        int k = tid;
        float nrm = 0.f;
        for (int c = 0; c < 16; ++c) { float v = cb[k * 16 + c]; nrm = fmaf(v, v, nrm); }
        for (int c = 0; c < 16; ++c) { gQ[QCB + k * 20 + c] = cb[k * 16 + c]; gI[ICB + k * 20 + c] = cb[k * 16 + c]; }
        gQ[QCB + k * 20 + 16] = nrm; gI[ICB + k * 20 + 16] = nrm;
        for (int c = 17; c < 20; ++c) { gQ[QCB + k * 20 + c] = 0.f; gI[ICB + k * 20 + c] = 0.f; }
        float dacc = db[0];
        for (int c = 0; c < 16; ++c) dacc = fmaf(dw[c], cb[k * 16 + c], dacc);
        dlut[k] = 1.f / (1.f + expf(-dacc));
        for (int c = 0; c < 16; ++c) {
            float ta = tb[c];
            for (int i = 0; i < 16; ++i) ta = fmaf(tw[c * 16 + i], cb[k * 16 + i], ta);
            float beta = 1.f / (1.f + expf(-ta));
            gQ[QAB + k * 20 + c] = beta * cb[k * 16 + c] + (1.f - beta) * b2[c];
            gQ[QAB + (32 + k) * 20 + c] = 1.f - beta;
        }
        for (int c = 16; c < 20; ++c) { gQ[QAB + k * 20 + c] = 0.f; gQ[QAB + (32 + k) * 20 + c] = 0.f; }
    }
    if (tid < 16) {
        int i = tid;
        for (int o = 0; o < 16; ++o) {
            gQ[QU2 + i * 16 + o] = u2w[o * 16 + i];
            gI[IU2 + i * 16 + o] = u2w[o * 16 + i];
            gI[ITA + i * 16 + o] = tw[o * 16 + i];   // tau^T
        }
        gI[IB1 + i] = b1[i]; gI[IB2 + i] = b2[i]; gI[ITB + i] = tb[i]; gI[ISB + i] = stb[i];
    }
    if (tid < 9) {
        int t = tid;
        for (int o = 0; o < 16; ++o) gI[ISW + t * 16 + o] = stw[o * 9 + t];
    }
}

// ---------------- step 1: stem + up1/up2/tau/blend + VQ, 2 px/thread ----------------
// (unchanged — measured-stable at ~215 us)
__global__ __launch_bounds__(256, 3) void k_iter1(
    const float* __restrict__ x, const float* __restrict__ gI,
    unsigned char* __restrict__ idx_out, double* __restrict__ lossS,
    unsigned int* __restrict__ maskS)
{
    __shared__ __align__(16) float xt[20 * 36];
    __shared__ __align__(16) float stE[306 * 20];   // even cols: 17 per row x 18 rows
    __shared__ __align__(16) float stO[306 * 20];   // odd cols
    __shared__ double dsum[4];
    __shared__ unsigned int msum[4];
    const int lx = threadIdx.x, ly = threadIdx.y;
    const int lid = ly * 16 + lx;
    const int b = blockIdx.z, oy = blockIdx.y * 16, ox = blockIdx.x * 32;
    const float* xb = x + (size_t)b * (H_ * W_);
    for (int i = lid; i < 720; i += 256) {
        int iy = i / 36, ix = i % 36;
        int gy = oy - 2 + iy, gx = ox - 2 + ix;
        float v = 0.f;
        if ((unsigned)gy < (unsigned)H_ && (unsigned)gx < (unsigned)W_) v = xb[gy * W_ + gx];
        xt[i] = v;
    }
    __syncthreads();
    for (int q = lid; q < 612; q += 256) {          // stem conv -> st (relu, zero outside)
        int sy = q / 34, sx = q % 34;
        int gy = oy - 1 + sy, gx = ox - 1 + sx;
        bool inb = ((unsigned)gy < (unsigned)H_ && (unsigned)gx < (unsigned)W_);
        V16 a = ld16(&gI[ISB]);
        #pragma unroll
        for (int t = 0; t < 9; ++t) {
            float xv = xt[(sy + t / 3) * 36 + sx + t % 3];
            V16 w = ld16(&gI[ISW + t * 16]);
            v16fma(a, w, xv);
        }
        v16relu(a);
        if (!inb) a = v16z();
        float* dst = ((sx & 1) ? stO : stE) + (sy * 17 + (sx >> 1)) * 20;
        st16(dst, a);
    }
    __syncthreads();
    V16 u0 = ld16(&gI[IB1]);
    V16 u1 = u0;
    #pragma unroll
    for (int t = 0; t < 9; ++t) {
        const int r = ly + t / 3, dx = t % 3;
        const float* p0; const float* p1;
        if (dx == 0)      { p0 = &stE[(r * 17 + lx) * 20];     p1 = &stO[(r * 17 + lx) * 20]; }
        else if (dx == 1) { p0 = &stO[(r * 17 + lx) * 20];     p1 = &stE[(r * 17 + lx + 1) * 20]; }
        else              { p0 = &stE[(r * 17 + lx + 1) * 20]; p1 = &stO[(r * 17 + lx + 1) * 20]; }
        V16 s0 = ld16(p0), s1 = ld16(p1);
        const int base = IW1 + t * 256;
        #pragma unroll
        for (int j = 0; j < 8; ++j) {
            f2v a0 = s0.h[j], a1 = s1.h[j];
            V16 wA = ld16(&gI[base + (2 * j) * 16]);
            v16fma(u0, wA, a0.x); v16fma(u1, wA, a1.x);
            V16 wB = ld16(&gI[base + (2 * j + 1) * 16]);
            v16fma(u0, wB, a0.y); v16fma(u1, wB, a1.y);
        }
    }
    v16relu(u0); v16relu(u1);
    V16 c0 = ld16(&stO[((ly + 1) * 17 + lx) * 20]);
    V16 c1 = ld16(&stE[((ly + 1) * 17 + lx + 1) * 20]);
    V16 v0 = ld16(&gI[IB2]);
    V16 v1 = v0;
    #pragma unroll
    for (int j = 0; j < 8; ++j) {
        f2v a0 = u0.h[j], a1 = u1.h[j];
        V16 wA = ld16(&gI[IU2 + (2 * j) * 16]);
        v16fma(v0, wA, a0.x); v16fma(v1, wA, a1.x);
        V16 wB = ld16(&gI[IU2 + (2 * j + 1) * 16]);
        v16fma(v0, wB, a0.y); v16fma(v1, wB, a1.y);
    }
    V16 t0 = ld16(&gI[ITB]);
    V16 t1 = t0;
    #pragma unroll
    for (int j = 0; j < 8; ++j) {
        f2v a0 = c0.h[j], a1 = c1.h[j];
        V16 wA = ld16(&gI[ITA + (2 * j) * 16]);
        v16fma(t0, wA, a0.x); v16fma(t1, wA, a1.x);
        V16 wB = ld16(&gI[ITA + (2 * j + 1) * 16]);
        v16fma(t0, wB, a0.y); v16fma(t1, wB, a1.y);
    }
    v16sig(t0); v16sig(t1);
    V16 z0, z1;
    #pragma unroll
    for (int j = 0; j < 8; ++j) {
        z0.h[j] = fma2(t0.h[j], c0.h[j] - v0.h[j], v0.h[j]);
        z1.h[j] = fma2(t1.h[j], c1.h[j] - v1.h[j], v1.h[j]);
    }
    float zz0 = v16dot(z0, z0), zz1 = v16dot(z1, z1);
    float best0 = 3.4e38f, best1 = 3.4e38f; int bk0 = 0, bk1 = 0;
    #pragma unroll 4
    for (int k = 0; k < 32; ++k) {
        V16 q = ld16(&gI[ICB + k * 20]);
        float cn = gI[ICB + k * 20 + 16];
        float d0 = (zz0 + cn) - 2.0f * v16dot(q, z0);
        float d1 = (zz1 + cn) - 2.0f * v16dot(q, z1);
        if (d0 < best0) { best0 = d0; bk0 = k; }
        if (d1 < best1) { best1 = d1; bk1 = k; }
    }
    unsigned short pr = (unsigned short)(bk0 | (bk1 << 8));
    *(unsigned short*)(idx_out + (size_t)b * (H_ * W_) + (size_t)(oy + ly) * W_ + ox + 2 * lx) = pr;
    float lp = best0 + best1;
    unsigned int m = (1u << bk0) | (1u << bk1);
    #pragma unroll
    for (int off = 32; off > 0; off >>= 1) {
        lp += __shfl_down(lp, off, 64);
        m |= __shfl_down(m, off, 64);
    }
    if ((lid & 63) == 0) { dsum[lid >> 6] = (double)lp; msum[lid >> 6] = m; }
    __syncthreads();
    if (lid == 0) {
        atomicAdd(lossS, dsum[0] + dsum[1] + dsum[2] + dsum[3]);
        atomicOr(maskS, msum[0] | msum[1] | msum[2] | msum[3]);
    }
}

// ---------------- fused double qstep: steps s (internal, LDS) + s+1 (output) ----------------
// Block owns a 128x16 tile of step s+1. Step-s codes are recomputed locally on a 130x18
// region (16% halo redundancy) from a 2-halo staging of step s-1 codes; never hit global.
__global__ __launch_bounds__(256, 4) void k_qstep2(
    const unsigned char* __restrict__ idx_in, unsigned char* __restrict__ idx_out,
    const float* __restrict__ gQ,
    double* __restrict__ lossA, unsigned int* __restrict__ maskA,
    double* __restrict__ lossB, unsigned int* __restrict__ maskB,
    float* __restrict__ out_px, const float* __restrict__ dlut)
{
    __shared__ __align__(16) float tab[QLDS];       // T9 + A2/Bc = 28,880 B
    __shared__ unsigned char ctA[20 * 144];         // step s-1 codes, 20 rows x 136 cols used
    __shared__ unsigned char ctB[18 * 144];         // step s   codes, 18 rows x 132 cols used
    __shared__ float lut[32];
    __shared__ double dsA[4], dsB[4];
    __shared__ unsigned int msA[4], msB[4];
    const int tx = threadIdx.x, ty = threadIdx.y;
    const int lid = ty * 16 + tx;
    const int b = blockIdx.z, oy = blockIdx.y * 16, ox = blockIdx.x * 128;
    for (int i = lid; i < QLDS / 4; i += 256) ((float4*)tab)[i] = ((const float4*)gQ)[i];
    if (lid < 32) lut[lid] = dlut[lid];
    const unsigned char* ib = idx_in + (size_t)b * (H_ * W_);
    for (int i = lid; i < 20 * 136; i += 256) {     // stage s-1 codes with 2-halo
        int r = i / 136, c = i % 136;
        int gy = oy - 2 + r, gx = ox - 2 + c;
        unsigned char v = 32;                       // sentinel -> zero vector
        if ((unsigned)gy < (unsigned)H_ && (unsigned)gx < (unsigned)W_) v = ib[gy * W_ + gx];
        ctA[r * 144 + c] = v;
    }
    __syncthreads();
    // ---- step s: region rows rr 0..17 (gy=oy-1+rr), cols cc 0..129 (gx=ox-1+cc) ----
    // 33 4-px groups per row x 18 rows = 594 groups
    float lpA = 0.f; unsigned int mA = 0u;
    for (int g = lid; g < 594; g += 256) {
        int rr = g / 33, c0 = (g % 33) * 4;
        int K[3][6];
        #pragma unroll
        for (int r = 0; r < 3; ++r) {
            unsigned int w0 = *(const unsigned int*)&ctA[(rr + r) * 144 + c0];
            unsigned int w1 = *(const unsigned int*)&ctA[(rr + r) * 144 + c0 + 4];
            K[r][0] = w0 & 255; K[r][1] = (w0 >> 8) & 255; K[r][2] = (w0 >> 16) & 255;
            K[r][3] = w0 >> 24; K[r][4] = w1 & 255; K[r][5] = (w1 >> 8) & 255;
        }
        int bk[4]; float best[4];
        group4(tab, gQ, K, bk, best);
        unsigned int pack = 0;
        #pragma unroll
        for (int p = 0; p < 4; ++p) {
            int cc = c0 + p;
            int gy = oy - 1 + rr, gx = ox - 1 + cc;
            bool valid = ((unsigned)gy < (unsigned)H_) && ((unsigned)gx < (unsigned)W_) && (cc < 130);
            unsigned int byte = valid ? (unsigned int)bk[p] : 32u;
            pack |= byte << (8 * p);
            bool owned = (rr >= 1) && (rr <= 16) && (cc >= 1) && (cc <= 128);
            if (owned) { lpA += best[p]; mA |= 1u << bk[p]; }
        }
        *(unsigned int*)&ctB[rr * 144 + c0] = pack;
    }
    __syncthreads();
    // ---- step s+1: 8 px/thread from ctB (exact R10 structure) ----
    const int cx = tx * 8;
    int K10[3][10];
    #pragma unroll
    for (int r = 0; r < 3; ++r) {
        unsigned int w0 = *(const unsigned int*)&ctB[(ty + r) * 144 + cx];
        unsigned int w1 = *(const unsigned int*)&ctB[(ty + r) * 144 + cx + 4];
        unsigned int w2 = *(const unsigned int*)&ctB[(ty + r) * 144 + cx + 8];
        K10[r][0] = w0 & 255; K10[r][1] = (w0 >> 8) & 255; K10[r][2] = (w0 >> 16) & 255; K10[r][3] = w0 >> 24;
        K10[r][4] = w1 & 255; K10[r][5] = (w1 >> 8) & 255; K10[r][6] = (w1 >> 16) & 255; K10[r][7] = w1 >> 24;
        K10[r][8] = w2 & 255; K10[r][9] = (w2 >> 8) & 255;
    }
    float lpB = 0.f; unsigned int mB = 0u;
    #pragma unroll
    for (int g = 0; g < 2; ++g) {
        const int gofs = g * 4;
        int K[3][6];
        #pragma unroll
        for (int r = 0; r < 3; ++r)
            #pragma unroll
            for (int j = 0; j < 6; ++j) K[r][j] = K10[r][gofs + j];
        int bk[4]; float best[4];
        group4(tab, gQ, K, bk, best);
        const size_t pofs = (size_t)b * (H_ * W_) + (size_t)(oy + ty) * W_ + ox + cx + gofs;
        if (out_px) {
            float4 o4 = make_float4(lut[bk[0]], lut[bk[1]], lut[bk[2]], lut[bk[3]]);
            *(float4*)(out_px + pofs) = o4;
        } else {
            unsigned int pack = (unsigned)bk[0] | ((unsigned)bk[1] << 8) |
                                ((unsigned)bk[2] << 16) | ((unsigned)bk[3] << 24);
            *(unsigned int*)(idx_out + pofs) = pack;
        }
        lpB += best[0] + best[1] + best[2] + best[3];
        mB |= (1u << bk[0]) | (1u << bk[1]) | (1u << bk[2]) | (1u << bk[3]);
    }
    // ---- reductions (both steps) ----
    #pragma unroll
    for (int off = 32; off > 0; off >>= 1) {
        lpA += __shfl_down(lpA, off, 64);
        mA |= __shfl_down(mA, off, 64);
        lpB += __shfl_down(lpB, off, 64);
        mB |= __shfl_down(mB, off, 64);
    }
    if ((lid & 63) == 0) {
        dsA[lid >> 6] = (double)lpA; msA[lid >> 6] = mA;
        dsB[lid >> 6] = (double)lpB; msB[lid >> 6] = mB;
    }
    __syncthreads();
    if (lid == 0) {
        atomicAdd(lossA, dsA[0] + dsA[1] + dsA[2] + dsA[3]);
        atomicOr(maskA, msA[0] | msA[1] | msA[2] | msA[3]);
        atomicAdd(lossB, dsB[0] + dsB[1] + dsB[2] + dsB[3]);
        atomicOr(maskB, msB[0] | msB[1] | msB[2] | msB[3]);
    }
}

// ---------------- scalar tail: loss / usage outputs ----------------
__global__ void k_scalars(float* __restrict__ out, const double* __restrict__ lossS,
                          const unsigned int* __restrict__ maskS)
{
    if (threadIdx.x == 0) {
        double vq = 0.0; float us = 0.f;
        for (int s = 0; s < 5; ++s) {
            vq += 1.25 * lossS[s] / 33554432.0;
            us += (float)__popc(maskS[s]) / 32.0f;
        }
        out[NPIX] = (float)(vq / 5.0);
        out[NPIX + 1] = us / 5.0f;
    }
}

extern "C" void kernel_launch(void* const* d_in, const int* in_sizes, int n_in,
                              void* d_out, int out_size, void* d_ws, size_t ws_size,
                              hipStream_t stream)
{
    const float* x   = (const float*)d_in[0];
    const float* stw = (const float*)d_in[1];
    const float* stb = (const float*)d_in[2];
    const float* w1  = (const float*)d_in[3];
    const float* b1  = (const float*)d_in[4];
    const float* u2w = (const float*)d_in[5];
    const float* b2  = (const float*)d_in[6];
    const float* tw  = (const float*)d_in[7];
    const float* tb  = (const float*)d_in[8];
    const float* cb  = (const float*)d_in[9];
    const float* dw  = (const float*)d_in[10];
    const float* db  = (const float*)d_in[11];

    char* ws = (char*)d_ws;
    unsigned char* idxA = (unsigned char*)ws;
    unsigned char* idxB = (unsigned char*)(ws + NPIX);
    float* gQ   = (float*)(ws + OFF_QTAB);
    float* gI   = (float*)(ws + OFF_ITAB);
    float* dlut = (float*)(ws + OFF_DLUT);
    double* lossS = (double*)(ws + OFF_LOSS);
    unsigned int* maskS = (unsigned int*)(ws + OFF_MASK);

    dim3 blk(16, 16, 1);
    dim3 g1(W_ / 32, H_ / 16, B_);      // iter1: 32x16 tiles, 2 px/thread
    dim3 gq(W_ / 128, H_ / 16, B_);     // fused qstep: 128x16 owned tiles (1024 blocks)
    float* out = (float*)d_out;
    k_setup<<<16, 256, 0, stream>>>(w1, b1, u2w, b2, tw, tb, cb, stw, stb, dw, db,
                                    gQ, gI, dlut, lossS, maskS);
    k_iter1<<<g1, blk, 0, stream>>>(x, gI, idxA, lossS + 0, maskS + 0);
    k_qstep2<<<gq, blk, 0, stream>>>(idxA, idxB, gQ, lossS + 1, maskS + 1,
                                     lossS + 2, maskS + 2, nullptr, dlut);
    k_qstep2<<<gq, blk, 0, stream>>>(idxB, idxA, gQ, lossS + 3, maskS + 3,
                                     lossS + 4, maskS + 4, out, dlut);
    k_scalars<<<1, 64, 0, stream>>>(out, lossS, maskS);
}

// Round 12
// 519.408 us; speedup vs baseline: 1.0606x; 1.0606x over previous
//
#include <hip/hip_runtime.h>
#include <math.h>

#define DEV __device__ __forceinline__

namespace {
constexpr int B_ = 32, H_ = 256, W_ = 256;
constexpr size_t NPIX = (size_t)B_ * H_ * W_;   // 2,097,152

// ---- qstep global table block (float offsets) ----
constexpr int QT9 = 0;            // [9][33] entries stride20: T9[t][code][o] (+b1 baked at t==4)
constexpr int QAB = 5940;         // A2: 32 entries stride20; then Bc: 32 entries stride20
constexpr int QCB = 7220;         // 32 entries stride20: cb + |cb|^2 (uniform -> SMEM)
constexpr int QU2 = 7860;         // 16 entries stride16: up2w^T (uniform -> SMEM)
constexpr int QTOT = 8116;
constexpr int QLDS = 7220;        // floats staged to LDS (divergent-gather tables: T9 + A2/Bc)

// ---- iter1 global table block ----
constexpr int IW1 = 0;            // [9*16] entries stride16: w1[t][i][o]
constexpr int IU2 = 2304;         // 16 entries stride16: up2w^T [i][o]
constexpr int ITA = 2560;         // 16 entries stride16: tauw^T [i][c]
constexpr int ICB = 2816;         // 32 entries stride20: cb + |cb|^2 at +16
constexpr int IB1 = 3456;
constexpr int IB2 = 3472;
constexpr int ITB = 3488;
constexpr int ISB = 3504;
constexpr int ISW = 3520;         // 9 entries stride16
constexpr int ITOT = 3664;

// ws byte offsets
constexpr size_t OFF_QTAB = 2 * NPIX;
constexpr size_t OFF_ITAB = OFF_QTAB + (size_t)QTOT * 4;
constexpr size_t OFF_DLUT = OFF_ITAB + (size_t)ITOT * 4;
constexpr size_t OFF_LOSS = (OFF_DLUT + 128 + 7) & ~(size_t)7;
constexpr size_t OFF_MASK = OFF_LOSS + 5 * 8;
}

typedef float f2v __attribute__((ext_vector_type(2)));

struct V16 { f2v h[8]; };

DEV f2v fma2(f2v a, f2v b, f2v c) {       // a*b + c, elementwise (-> v_pk_fma_f32)
#if __has_builtin(__builtin_elementwise_fma)
    return __builtin_elementwise_fma(a, b, c);
#else
    f2v r; r.x = fmaf(a.x, b.x, c.x); r.y = fmaf(a.y, b.y, c.y); return r;
#endif
}
DEV f2v max2(f2v a, f2v b) {
#if __has_builtin(__builtin_elementwise_max)
    return __builtin_elementwise_max(a, b);
#else
    f2v r; r.x = fmaxf(a.x, b.x); r.y = fmaxf(a.y, b.y); return r;
#endif
}

DEV V16 v16z() {
    V16 r;
    #pragma unroll
    for (int j = 0; j < 8; ++j) r.h[j] = (f2v){0.f, 0.f};
    return r;
}
DEV void v16fma(V16& a, const V16& w, float s) {
    f2v ss = (f2v){s, s};
    #pragma unroll
    for (int j = 0; j < 8; ++j) a.h[j] = fma2(w.h[j], ss, a.h[j]);
}
DEV void v16add(V16& a, const V16& b) {
    #pragma unroll
    for (int j = 0; j < 8; ++j) a.h[j] = a.h[j] + b.h[j];
}
DEV void v16relu(V16& a) {
    f2v z = (f2v){0.f, 0.f};
    #pragma unroll
    for (int j = 0; j < 8; ++j) a.h[j] = max2(a.h[j], z);
}
DEV float v16dot(const V16& a, const V16& b) {
    f2v acc = (f2v){0.f, 0.f};
    #pragma unroll
    for (int j = 0; j < 8; ++j) acc = fma2(a.h[j], b.h[j], acc);
    return acc.x + acc.y;
}
DEV V16 ld16(const float* p) {            // 4x ds_read_b128 / s_load
    const float4* q = (const float4*)p;
    float4 A = q[0], Bv = q[1], C = q[2], D = q[3];
    V16 r;
    r.h[0] = (f2v){A.x, A.y};  r.h[1] = (f2v){A.z, A.w};
    r.h[2] = (f2v){Bv.x, Bv.y}; r.h[3] = (f2v){Bv.z, Bv.w};
    r.h[4] = (f2v){C.x, C.y};  r.h[5] = (f2v){C.z, C.w};
    r.h[6] = (f2v){D.x, D.y};  r.h[7] = (f2v){D.z, D.w};
    return r;
}
DEV void st16(float* p, const V16& v) {
    float4* q = (float4*)p;
    q[0] = make_float4(v.h[0].x, v.h[0].y, v.h[1].x, v.h[1].y);
    q[1] = make_float4(v.h[2].x, v.h[2].y, v.h[3].x, v.h[3].y);
    q[2] = make_float4(v.h[4].x, v.h[4].y, v.h[5].x, v.h[5].y);
    q[3] = make_float4(v.h[6].x, v.h[6].y, v.h[7].x, v.h[7].y);
}
DEV void v16sig(V16& a) {
    #pragma unroll
    for (int j = 0; j < 8; ++j) {
        a.h[j].x = 1.f / (1.f + expf(-a.h[j].x));
        a.h[j].y = 1.f / (1.f + expf(-a.h[j].y));
    }
}

// ---------------- setup: parallel across 16 blocks ----------------
__global__ void k_setup(const float* __restrict__ w1, const float* __restrict__ b1,
                        const float* __restrict__ u2w, const float* __restrict__ b2,
                        const float* __restrict__ tw, const float* __restrict__ tb,
                        const float* __restrict__ cb, const float* __restrict__ stw,
                        const float* __restrict__ stb, const float* __restrict__ dw,
                        const float* __restrict__ db,
                        float* __restrict__ gQ, float* __restrict__ gI,
                        float* __restrict__ dlut, double* __restrict__ lossS,
                        unsigned int* __restrict__ maskS)
{
    const int tid = threadIdx.x;
    const int gtid = blockIdx.x * 256 + tid;    // 0..4095
    if (gtid < 5) { lossS[gtid] = 0.0; maskS[gtid] = 0u; }
    for (int p = gtid; p < 297 * 16; p += 4096) {   // T9 entry-output pairs
        int e = p >> 4, o = p & 15;
        int t = e / 33, k = e % 33;
        float acc = 0.f;
        if (k < 32) {
            for (int i = 0; i < 16; ++i)
                acc = fmaf(w1[o * 144 + i * 9 + t], cb[k * 16 + i], acc);
            if (t == 4) acc += b1[o];
        }
        gQ[QT9 + e * 20 + o] = acc;
    }
    for (int e = gtid; e < 297; e += 4096) {        // T9 pads
        gQ[QT9 + e * 20 + 16] = 0.f; gQ[QT9 + e * 20 + 17] = 0.f;
        gQ[QT9 + e * 20 + 18] = 0.f; gQ[QT9 + e * 20 + 19] = 0.f;
    }
    for (int p = gtid; p < 144 * 16; p += 4096) {   // w1 rearranged [t][i][o]
        int e = p >> 4, o = p & 15;
        int t = e / 16, i = e % 16;
        gI[IW1 + e * 16 + o] = w1[o * 144 + i * 9 + t];
    }
    if (blockIdx.x != 0) return;
    if (tid < 32) {
        int k = tid;
        float nrm = 0.f;
        for (int c = 0; c < 16; ++c) { float v = cb[k * 16 + c]; nrm = fmaf(v, v, nrm); }
        for (int c = 0; c < 16; ++c) { gQ[QCB + k * 20 + c] = cb[k * 16 + c]; gI[ICB + k * 20 + c] = cb[k * 16 + c]; }
        gQ[QCB + k * 20 + 16] = nrm; gI[ICB + k * 20 + 16] = nrm;
        for (int c = 17; c < 20; ++c) { gQ[QCB + k * 20 + c] = 0.f; gI[ICB + k * 20 + c] = 0.f; }
        float dacc = db[0];
        for (int c = 0; c < 16; ++c) dacc = fmaf(dw[c], cb[k * 16 + c], dacc);
        dlut[k] = 1.f / (1.f + expf(-dacc));
        for (int c = 0; c < 16; ++c) {
            float ta = tb[c];
            for (int i = 0; i < 16; ++i) ta = fmaf(tw[c * 16 + i], cb[k * 16 + i], ta);
            float beta = 1.f / (1.f + expf(-ta));
            gQ[QAB + k * 20 + c] = beta * cb[k * 16 + c] + (1.f - beta) * b2[c];
            gQ[QAB + (32 + k) * 20 + c] = 1.f - beta;
        }
        for (int c = 16; c < 20; ++c) { gQ[QAB + k * 20 + c] = 0.f; gQ[QAB + (32 + k) * 20 + c] = 0.f; }
    }
    if (tid < 16) {
        int i = tid;
        for (int o = 0; o < 16; ++o) {
            gQ[QU2 + i * 16 + o] = u2w[o * 16 + i];
            gI[IU2 + i * 16 + o] = u2w[o * 16 + i];
            gI[ITA + i * 16 + o] = tw[o * 16 + i];   // tau^T
        }
        gI[IB1 + i] = b1[i]; gI[IB2 + i] = b2[i]; gI[ITB + i] = tb[i]; gI[ISB + i] = stb[i];
    }
    if (tid < 9) {
        int t = tid;
        for (int o = 0; o < 16; ++o) gI[ISW + t * 16 + o] = stw[o * 9 + t];
    }
}

// ---------------- step 1: stem + up1/up2/tau/blend + VQ, 2 px/thread ----------------
// (unchanged — measured-stable at ~215 us)
__global__ __launch_bounds__(256, 3) void k_iter1(
    const float* __restrict__ x, const float* __restrict__ gI,
    unsigned char* __restrict__ idx_out, double* __restrict__ lossS,
    unsigned int* __restrict__ maskS)
{
    __shared__ __align__(16) float xt[20 * 36];
    __shared__ __align__(16) float stE[306 * 20];   // even cols: 17 per row x 18 rows
    __shared__ __align__(16) float stO[306 * 20];   // odd cols
    __shared__ double dsum[4];
    __shared__ unsigned int msum[4];
    const int lx = threadIdx.x, ly = threadIdx.y;
    const int lid = ly * 16 + lx;
    const int b = blockIdx.z, oy = blockIdx.y * 16, ox = blockIdx.x * 32;
    const float* xb = x + (size_t)b * (H_ * W_);
    for (int i = lid; i < 720; i += 256) {
        int iy = i / 36, ix = i % 36;
        int gy = oy - 2 + iy, gx = ox - 2 + ix;
        float v = 0.f;
        if ((unsigned)gy < (unsigned)H_ && (unsigned)gx < (unsigned)W_) v = xb[gy * W_ + gx];
        xt[i] = v;
    }
    __syncthreads();
    for (int q = lid; q < 612; q += 256) {          // stem conv -> st (relu, zero outside)
        int sy = q / 34, sx = q % 34;
        int gy = oy - 1 + sy, gx = ox - 1 + sx;
        bool inb = ((unsigned)gy < (unsigned)H_ && (unsigned)gx < (unsigned)W_);
        V16 a = ld16(&gI[ISB]);
        #pragma unroll
        for (int t = 0; t < 9; ++t) {
            float xv = xt[(sy + t / 3) * 36 + sx + t % 3];
            V16 w = ld16(&gI[ISW + t * 16]);
            v16fma(a, w, xv);
        }
        v16relu(a);
        if (!inb) a = v16z();
        float* dst = ((sx & 1) ? stO : stE) + (sy * 17 + (sx >> 1)) * 20;
        st16(dst, a);
    }
    __syncthreads();
    V16 u0 = ld16(&gI[IB1]);
    V16 u1 = u0;
    #pragma unroll
    for (int t = 0; t < 9; ++t) {
        const int r = ly + t / 3, dx = t % 3;
        const float* p0; const float* p1;
        if (dx == 0)      { p0 = &stE[(r * 17 + lx) * 20];     p1 = &stO[(r * 17 + lx) * 20]; }
        else if (dx == 1) { p0 = &stO[(r * 17 + lx) * 20];     p1 = &stE[(r * 17 + lx + 1) * 20]; }
        else              { p0 = &stE[(r * 17 + lx + 1) * 20]; p1 = &stO[(r * 17 + lx + 1) * 20]; }
        V16 s0 = ld16(p0), s1 = ld16(p1);
        const int base = IW1 + t * 256;
        #pragma unroll
        for (int j = 0; j < 8; ++j) {
            f2v a0 = s0.h[j], a1 = s1.h[j];
            V16 wA = ld16(&gI[base + (2 * j) * 16]);
            v16fma(u0, wA, a0.x); v16fma(u1, wA, a1.x);
            V16 wB = ld16(&gI[base + (2 * j + 1) * 16]);
            v16fma(u0, wB, a0.y); v16fma(u1, wB, a1.y);
        }
    }
    v16relu(u0); v16relu(u1);
    V16 c0 = ld16(&stO[((ly + 1) * 17 + lx) * 20]);
    V16 c1 = ld16(&stE[((ly + 1) * 17 + lx + 1) * 20]);
    V16 v0 = ld16(&gI[IB2]);
    V16 v1 = v0;
    #pragma unroll
    for (int j = 0; j < 8; ++j) {
        f2v a0 = u0.h[j], a1 = u1.h[j];
        V16 wA = ld16(&gI[IU2 + (2 * j) * 16]);
        v16fma(v0, wA, a0.x); v16fma(v1, wA, a1.x);
        V16 wB = ld16(&gI[IU2 + (2 * j + 1) * 16]);
        v16fma(v0, wB, a0.y); v16fma(v1, wB, a1.y);
    }
    V16 t0 = ld16(&gI[ITB]);
    V16 t1 = t0;
    #pragma unroll
    for (int j = 0; j < 8; ++j) {
        f2v a0 = c0.h[j], a1 = c1.h[j];
        V16 wA = ld16(&gI[ITA + (2 * j) * 16]);
        v16fma(t0, wA, a0.x); v16fma(t1, wA, a1.x);
        V16 wB = ld16(&gI[ITA + (2 * j + 1) * 16]);
        v16fma(t0, wB, a0.y); v16fma(t1, wB, a1.y);
    }
    v16sig(t0); v16sig(t1);
    V16 z0, z1;
    #pragma unroll
    for (int j = 0; j < 8; ++j) {
        z0.h[j] = fma2(t0.h[j], c0.h[j] - v0.h[j], v0.h[j]);
        z1.h[j] = fma2(t1.h[j], c1.h[j] - v1.h[j], v1.h[j]);
    }
    float zz0 = v16dot(z0, z0), zz1 = v16dot(z1, z1);
    float best0 = 3.4e38f, best1 = 3.4e38f; int bk0 = 0, bk1 = 0;
    #pragma unroll 4
    for (int k = 0; k < 32; ++k) {
        V16 q = ld16(&gI[ICB + k * 20]);
        float cn = gI[ICB + k * 20 + 16];
        float d0 = (zz0 + cn) - 2.0f * v16dot(q, z0);
        float d1 = (zz1 + cn) - 2.0f * v16dot(q, z1);
        if (d0 < best0) { best0 = d0; bk0 = k; }
        if (d1 < best1) { best1 = d1; bk1 = k; }
    }
    unsigned short pr = (unsigned short)(bk0 | (bk1 << 8));
    *(unsigned short*)(idx_out + (size_t)b * (H_ * W_) + (size_t)(oy + ly) * W_ + ox + 2 * lx) = pr;
    float lp = best0 + best1;
    unsigned int m = (1u << bk0) | (1u << bk1);
    #pragma unroll
    for (int off = 32; off > 0; off >>= 1) {
        lp += __shfl_down(lp, off, 64);
        m |= __shfl_down(m, off, 64);
    }
    if ((lid & 63) == 0) { dsum[lid >> 6] = (double)lp; msum[lid >> 6] = m; }
    __syncthreads();
    if (lid == 0) {
        atomicAdd(lossS, dsum[0] + dsum[1] + dsum[2] + dsum[3]);
        atomicOr(maskS, msum[0] | msum[1] | msum[2] | msum[3]);
    }
}

// ---------------- steps 2..5: 128x16 tile, 8 px/thread (two sequential 4-px groups) ----------------
// Grid = 1024 blocks = 256 CU x 4; launch_bounds(256,4) -> ALL blocks resident, staging
// fully overlapped. (R10 measured-best structure, unchanged.)
__global__ __launch_bounds__(256, 4) void k_qstep(
    const unsigned char* __restrict__ idx_in, unsigned char* __restrict__ idx_out,
    const float* __restrict__ gQ, double* __restrict__ lossS,
    unsigned int* __restrict__ maskS, float* __restrict__ out_px,
    const float* __restrict__ dlut)
{
    __shared__ __align__(16) float tab[QLDS];       // T9 (5940) + A2/Bc (1280) = 28,880 B
    __shared__ unsigned char ct[18 * 144];          // 18 rows x 130 cols used
    __shared__ float lut[32];
    __shared__ double dsum[4];
    __shared__ unsigned int msum[4];
    const int tx = threadIdx.x, ty = threadIdx.y;
    const int lid = ty * 16 + tx;
    const int b = blockIdx.z, oy = blockIdx.y * 16, ox = blockIdx.x * 128;
    for (int i = lid; i < QLDS / 4; i += 256) ((float4*)tab)[i] = ((const float4*)gQ)[i];
    if (lid < 32) lut[lid] = dlut[lid];
    const unsigned char* ib = idx_in + (size_t)b * (H_ * W_);
    for (int i = lid; i < 18 * 130; i += 256) {
        int r = i / 130, c = i % 130;
        int gy = oy - 1 + r, gx = ox - 1 + c;
        unsigned char v = 32;               // sentinel -> zero vector
        if ((unsigned)gy < (unsigned)H_ && (unsigned)gx < (unsigned)W_) v = ib[gy * W_ + gx];
        ct[r * 144 + c] = v;
    }
    __syncthreads();
    const int cx = tx * 8;
    int K[3][10];
    #pragma unroll
    for (int r = 0; r < 3; ++r) {
        unsigned int w0 = *(const unsigned int*)&ct[(ty + r) * 144 + cx];
        unsigned int w1 = *(const unsigned int*)&ct[(ty + r) * 144 + cx + 4];
        unsigned int w2 = *(const unsigned int*)&ct[(ty + r) * 144 + cx + 8];
        K[r][0] = w0 & 255; K[r][1] = (w0 >> 8) & 255; K[r][2] = (w0 >> 16) & 255; K[r][3] = w0 >> 24;
        K[r][4] = w1 & 255; K[r][5] = (w1 >> 8) & 255; K[r][6] = (w1 >> 16) & 255; K[r][7] = w1 >> 24;
        K[r][8] = w2 & 255; K[r][9] = (w2 >> 8) & 255;
    }
    float lpT = 0.f;
    unsigned int mT = 0u;
    #pragma unroll
    for (int g = 0; g < 2; ++g) {           // two 4-px groups, fully sequential
        const int gofs = g * 4;             // K column offset for this group
        V16 V[4];
        #pragma unroll
        for (int half = 0; half < 2; ++half) {
            const int p0 = half * 2, p1 = half * 2 + 1;
            V16 U0 = v16z(), U1 = v16z();
            #pragma unroll
            for (int t = 0; t < 9; ++t) {   // up1 = 9 gather-adds per px (LDS)
                const int dy = t / 3, dx = t % 3;
                V16 e0 = ld16(&tab[(t * 33 + K[dy][gofs + p0 + dx]) * 20]);
                v16add(U0, e0);
                V16 e1 = ld16(&tab[(t * 33 + K[dy][gofs + p1 + dx]) * 20]);
                v16add(U1, e1);
            }
            v16relu(U0); v16relu(U1);
            // up2 (uniform weights from global; b2 baked into A2)
            V16 v0 = v16z(), v1 = v16z();
            #pragma unroll
            for (int j = 0; j < 8; ++j) {
                f2v a0 = U0.h[j], a1 = U1.h[j];
                V16 wA = ld16(&gQ[QU2 + (2 * j) * 16]);
                v16fma(v0, wA, a0.x); v16fma(v1, wA, a1.x);
                V16 wB = ld16(&gQ[QU2 + (2 * j + 1) * 16]);
                v16fma(v0, wB, a0.y); v16fma(v1, wB, a1.y);
            }
            // blend via per-code tables (LDS gather): z = A2[kc] + Bc[kc]*v
            {
                int kc = K[1][gofs + p0 + 1];
                V16 a = ld16(&tab[QAB + kc * 20]);
                V16 bb = ld16(&tab[QAB + (32 + kc) * 20]);
                #pragma unroll
                for (int j = 0; j < 8; ++j) v0.h[j] = fma2(bb.h[j], v0.h[j], a.h[j]);
            }
            {
                int kc = K[1][gofs + p1 + 1];
                V16 a = ld16(&tab[QAB + kc * 20]);
                V16 bb = ld16(&tab[QAB + (32 + kc) * 20]);
                #pragma unroll
                for (int j = 0; j < 8; ++j) v1.h[j] = fma2(bb.h[j], v1.h[j], a.h[j]);
            }
            V[p0] = v0; V[p1] = v1;
        }
        // VQ this 4-px group: codebook streamed once (uniform -> SGPRs)
        float zz[4], best[4]; int bk[4];
        #pragma unroll
        for (int p = 0; p < 4; ++p) { zz[p] = v16dot(V[p], V[p]); best[p] = 3.4e38f; bk[p] = 0; }
        #pragma unroll 4
        for (int k = 0; k < 32; ++k) {
            V16 q = ld16(&gQ[QCB + k * 20]);
            float cn = gQ[QCB + k * 20 + 16];
            #pragma unroll
            for (int p = 0; p < 4; ++p) {
                float d = (zz[p] + cn) - 2.0f * v16dot(q, V[p]);
                if (d < best[p]) { best[p] = d; bk[p] = k; }
            }
        }
        const size_t pofs = (size_t)b * (H_ * W_) + (size_t)(oy + ty) * W_ + ox + cx + gofs;
        if (out_px) {
            float4 o4 = make_float4(lut[bk[0]], lut[bk[1]], lut[bk[2]], lut[bk[3]]);
            *(float4*)(out_px + pofs) = o4;
        } else {
            unsigned int pack = (unsigned)bk[0] | ((unsigned)bk[1] << 8) |
                                ((unsigned)bk[2] << 16) | ((unsigned)bk[3] << 24);
            *(unsigned int*)(idx_out + pofs) = pack;
        }
        lpT += best[0] + best[1] + best[2] + best[3];
        mT |= (1u << bk[0]) | (1u << bk[1]) | (1u << bk[2]) | (1u << bk[3]);
    }
    #pragma unroll
    for (int off = 32; off > 0; off >>= 1) {
        lpT += __shfl_down(lpT, off, 64);
        mT |= __shfl_down(mT, off, 64);
    }
    if ((lid & 63) == 0) { dsum[lid >> 6] = (double)lpT; msum[lid >> 6] = mT; }
    __syncthreads();
    if (lid == 0) {
        atomicAdd(lossS, dsum[0] + dsum[1] + dsum[2] + dsum[3]);
        atomicOr(maskS, msum[0] | msum[1] | msum[2] | msum[3]);
    }
}

// ---------------- scalar tail: loss / usage outputs ----------------
__global__ void k_scalars(float* __restrict__ out, const double* __restrict__ lossS,
                          const unsigned int* __restrict__ maskS)
{
    if (threadIdx.x == 0) {
        double vq = 0.0; float us = 0.f;
        for (int s = 0; s < 5; ++s) {
            vq += 1.25 * lossS[s] / 33554432.0;
            us += (float)__popc(maskS[s]) / 32.0f;
        }
        out[NPIX] = (float)(vq / 5.0);
        out[NPIX + 1] = us / 5.0f;
    }
}

extern "C" void kernel_launch(void* const* d_in, const int* in_sizes, int n_in,
                              void* d_out, int out_size, void* d_ws, size_t ws_size,
                              hipStream_t stream)
{
    const float* x   = (const float*)d_in[0];
    const float* stw = (const float*)d_in[1];
    const float* stb = (const float*)d_in[2];
    const float* w1  = (const float*)d_in[3];
    const float* b1  = (const float*)d_in[4];
    const float* u2w = (const float*)d_in[5];
    const float* b2  = (const float*)d_in[6];
    const float* tw  = (const float*)d_in[7];
    const float* tb  = (const float*)d_in[8];
    const float* cb  = (const float*)d_in[9];
    const float* dw  = (const float*)d_in[10];
    const float* db  = (const float*)d_in[11];

    char* ws = (char*)d_ws;
    unsigned char* idxA = (unsigned char*)ws;
    unsigned char* idxB = (unsigned char*)(ws + NPIX);
    float* gQ   = (float*)(ws + OFF_QTAB);
    float* gI   = (float*)(ws + OFF_ITAB);
    float* dlut = (float*)(ws + OFF_DLUT);
    double* lossS = (double*)(ws + OFF_LOSS);
    unsigned int* maskS = (unsigned int*)(ws + OFF_MASK);

    dim3 blk(16, 16, 1);
    dim3 g1(W_ / 32, H_ / 16, B_);      // iter1: 32x16 tiles, 2 px/thread
    dim3 gq(W_ / 128, H_ / 16, B_);     // qstep: 128x16 tiles, 8 px/thread (1024 blocks)
    float* out = (float*)d_out;
    k_setup<<<16, 256, 0, stream>>>(w1, b1, u2w, b2, tw, tb, cb, stw, stb, dw, db,
                                    gQ, gI, dlut, lossS, maskS);
    k_iter1<<<g1, blk, 0, stream>>>(x, gI, idxA, lossS + 0, maskS + 0);
    k_qstep<<<gq, blk, 0, stream>>>(idxA, idxB, gQ, lossS + 1, maskS + 1, nullptr, dlut);
    k_qstep<<<gq, blk, 0, stream>>>(idxB, idxA, gQ, lossS + 2, maskS + 2, nullptr, dlut);
    k_qstep<<<gq, blk, 0, stream>>>(idxA, idxB, gQ, lossS + 3, maskS + 3, nullptr, dlut);
    k_qstep<<<gq, blk, 0, stream>>>(idxB, idxA, gQ, lossS + 4, maskS + 4, out, dlut);
    k_scalars<<<1, 64, 0, stream>>>(out, lossS, maskS);
}